// Round 4
// baseline (730.493 us; speedup 1.0000x reference)
//
#include <hip/hip_runtime.h>
#include <hip/hip_cooperative_groups.h>
#include <math.h>

namespace cg = cooperative_groups;

#define Vv   50000
#define EMB  128
#define Hh   256
#define TKk  400
#define Bb   128
#define OOVn 10
#define N2n  512
#define VOo  50010   // V + OOV
#define NTILE 3125   // 50000 / 16 col-tiles
#define PSTR 3200    // partial stride >= NTILE
#define GRID 256
#define NWAVE 4096   // GRID * 16

typedef __bf16 bf16x8 __attribute__((ext_vector_type(8)));
typedef float  f32x4  __attribute__((ext_vector_type(4)));

__device__ __forceinline__ float sigf(float x) { return 1.f / (1.f + __expf(-x)); }
__device__ __forceinline__ float tanh_fast(float x) {
    x = fminf(15.f, fmaxf(-15.f, x));
    float e = __expf(2.f * x);
    return (e - 1.f) / (e + 1.f);
}
__device__ __forceinline__ float wave_red(float v) {
    #pragma unroll
    for (int o = 32; o; o >>= 1) v += __shfl_down(v, o);
    return v;
}
__device__ __forceinline__ float wave_max(float v) {
    #pragma unroll
    for (int o = 32; o; o >>= 1) v = fmaxf(v, __shfl_down(v, o));
    return v;
}
// fp32 -> bf16 RNE
__device__ __forceinline__ unsigned short f2bf(float f) {
    unsigned u = __builtin_bit_cast(unsigned, f);
    unsigned r = u + 0x7fffu + ((u >> 16) & 1u);
    return (unsigned short)(r >> 16);
}

struct MegaArgs {
    const int* y; const float* ct1; const float* emb;
    const float* Wx; const float* bx;
    const float* h0; const float* c0;
    const float* wih; const float* bih; const float* whh; const float* bhh;
    const float* Wp; const float* bp;
    const float* ef; const float* covi; const float* Wc; const float* vw;
    const float* mask; const float* eo;
    const float* W1; const float* b1; const float* Wpg; const float* bpg;
    const float* W2; const float* b2;
    const float* xz; const int* ebev;
    float* h1o; float* c1o; float* cto; float* attno; float* covo; float* pgo;
    float* fd;
    float* xw; float* dfw; float* scw; float* pM; float* pS;
    unsigned short* abf;
};

// ---------------------------------------------------------------------------
// One cooperative kernel: every phase at full device width; phase boundaries
// are grid.sync() instead of kernel launches. Bodies lifted from the
// round-1-verified kernels, re-indexed by global wave id gw in [0, 4096).
// ---------------------------------------------------------------------------
__global__ __launch_bounds__(1024, 4) void k_mega(MegaArgs A)
{
    cg::grid_group grid = cg::this_grid();
    const int tid = threadIdx.x;
    const int g = blockIdx.x;
    const int wv = tid >> 6, l = tid & 63;
    const int gw = g * 16 + wv;

    __shared__ float s_av[256];
    __shared__ float s_red[16];
    __shared__ float s_b[2];

    // ---- P0: zero cto (for P6 atomics) + x = concat(ct1, emb[y]) @ Wx^T + bx
    {
        int fid = g * 1024 + tid;
        if (fid < Bb * N2n) A.cto[fid] = 0.f;

        int j = gw & 127, b0 = (gw >> 7) * 4;   // 128 j x 32 b4 = 4096 tasks
        float w[10];
        #pragma unroll
        for (int i = 0; i < 10; i++) w[i] = A.Wx[(size_t)j * 640 + l + 64 * i];
        float bj = A.bx[j];
        #pragma unroll
        for (int bi = 0; bi < 4; bi++) {
            int b = b0 + bi;
            int yy = A.y[b];
            float a = 0.f;
            #pragma unroll
            for (int i = 0; i < 8; i++) a += A.ct1[b * 512 + l + 64 * i] * w[i];
            #pragma unroll
            for (int i = 0; i < 2; i++) a += A.emb[(size_t)yy * 128 + l + 64 * i] * w[8 + i];
            a = wave_red(a);
            if (l == 0) A.xw[b * 128 + j] = a + bj;
        }
    }
    grid.sync();

    // ---- P2: gates + LSTM. task = (b, n4); wave computes all 4 gates.
    for (int task = gw; task < Bb * 64; task += NWAVE) {
        int b = task >> 6, n4 = (task & 63) * 4;
        #pragma unroll
        for (int c = 0; c < 4; c++) {
            int n = n4 + c;
            float gsum[4];
            #pragma unroll
            for (int gi = 0; gi < 4; gi++) {
                int j = gi * 256 + n;
                float a = A.xw[b * 128 + l] * A.wih[(size_t)j * 128 + l]
                        + A.xw[b * 128 + l + 64] * A.wih[(size_t)j * 128 + l + 64];
                #pragma unroll
                for (int i = 0; i < 4; i++)
                    a += A.h0[b * 256 + l + 64 * i] * A.whh[(size_t)j * 256 + l + 64 * i];
                a = wave_red(a);
                gsum[gi] = a + A.bih[j] + A.bhh[j];
            }
            if (l == 0) {
                float ig = sigf(gsum[0]);
                float fg = sigf(gsum[1]);
                float gg = tanh_fast(gsum[2]);
                float og = sigf(gsum[3]);
                float c1 = fg * A.c0[b * 256 + n] + ig * gg;
                float h1 = og * tanh_fast(c1);
                A.h1o[b * 256 + n] = h1;
                A.c1o[b * 256 + n] = c1;
            }
        }
    }
    grid.sync();

    // ---- P3: dec_fea = [h1,c1] @ Wp^T + bp. task = (j, b4)
    for (int task = gw; task < 512 * 32; task += NWAVE) {
        int j = task >> 5, b0 = (task & 31) * 4;
        float w[8];
        #pragma unroll
        for (int i = 0; i < 8; i++) w[i] = A.Wp[(size_t)j * 512 + l + 64 * i];
        float bj = A.bp[j];
        #pragma unroll
        for (int bi = 0; bi < 4; bi++) {
            int b = b0 + bi;
            float a = 0.f;
            #pragma unroll
            for (int i = 0; i < 4; i++) a += A.h1o[b * 256 + l + 64 * i] * w[i];
            #pragma unroll
            for (int i = 0; i < 4; i++) a += A.c1o[b * 256 + l + 64 * i] * w[4 + i];
            a = wave_red(a);
            if (l == 0) A.dfw[b * 512 + j] = a + bj;
        }
    }
    grid.sync();

    // ---- P4: scores (streams ef, 105 MB — full width)
    for (int idx = gw; idx < Bb * TKk; idx += NWAVE) {
        int b = idx / TKk;
        const float* e = A.ef + (size_t)idx * N2n;
        const float* d = A.dfw + (size_t)b * N2n;
        float cv = A.covi[idx];
        float acc = 0.f;
        #pragma unroll
        for (int i = 0; i < 2; i++) {
            int n0 = l * 4 + i * 256;
            float4 ev = *(const float4*)(e + n0);
            float4 dv = *(const float4*)(d + n0);
            float4 wc = *(const float4*)(A.Wc + n0);
            float4 vv = *(const float4*)(A.vw + n0);
            acc += tanh_fast(ev.x + dv.x + cv * wc.x) * vv.x;
            acc += tanh_fast(ev.y + dv.y + cv * wc.y) * vv.y;
            acc += tanh_fast(ev.z + dv.z + cv * wc.z) * vv.z;
            acc += tanh_fast(ev.w + dv.w + cv * wc.w) * vv.w;
        }
        acc = wave_red(acc);
        if (l == 0) A.scw[idx] = acc;
    }
    grid.sync();

    // ---- P5: masked softmax + coverage (block per b, blocks 0..127)
    if (g < Bb) {
        int b = g;
        float s = (tid < TKk) ? A.scw[b * TKk + tid] : -3.4e38f;
        float m = wave_max(s);
        if (l == 0) s_red[wv] = m;
        __syncthreads();
        if (tid == 0) {
            float t = s_red[0];
            for (int i = 1; i < 16; i++) t = fmaxf(t, s_red[i]);
            s_b[0] = t;
        }
        __syncthreads();
        float M = s_b[0];
        float w = (tid < TKk) ? __expf(s - M) * A.mask[b * TKk + tid] : 0.f;
        float ss = wave_red(w);
        if (l == 0) s_red[wv] = ss;
        __syncthreads();
        if (tid == 0) {
            float t = 0.f;
            for (int i = 0; i < 16; i++) t += s_red[i];
            s_b[1] = t;
        }
        __syncthreads();
        float a = w / s_b[1];
        if (tid < TKk) {
            A.attno[b * TKk + tid] = a;
            A.covo[b * TKk + tid] = A.covi[b * TKk + tid] + a;
        }
    }
    grid.sync();

    // ---- P6: ctx (streams eo, 105 MB — full width). block = (b, half of t)
    {
        int b = g >> 1, half = g & 1;
        if (tid < 200) s_av[tid] = A.attno[b * TKk + half * 200 + tid];
        __syncthreads();
        int n = tid & 511, sub = tid >> 9;
        const float* p = A.eo + ((size_t)(b * TKk + half * 200 + sub * 100)) * N2n + n;
        float acc = 0.f;
        #pragma unroll 4
        for (int t = 0; t < 100; t++) acc += s_av[sub * 100 + t] * p[(size_t)t * N2n];
        atomicAdd(A.cto + b * N2n + n, acc);
    }
    grid.sync();

    // ---- P7: out = [h1,ct] @ W1^T + b1 -> abf (bf16); and p_gen
    for (int task = gw; task < 256 * 32; task += NWAVE) {
        int j = task >> 5, b0 = (task & 31) * 4;
        float w[12];
        #pragma unroll
        for (int i = 0; i < 12; i++) w[i] = A.W1[(size_t)j * 768 + l + 64 * i];
        float bj = A.b1[j];
        #pragma unroll
        for (int bi = 0; bi < 4; bi++) {
            int b = b0 + bi;
            float a = 0.f;
            #pragma unroll
            for (int i = 0; i < 4; i++) a += A.h1o[b * 256 + l + 64 * i] * w[i];
            #pragma unroll
            for (int i = 0; i < 8; i++) a += A.cto[b * 512 + l + 64 * i] * w[4 + i];
            a = wave_red(a);
            if (l == 0) A.abf[b * 256 + j] = f2bf(a + bj);
        }
    }
    if (gw < Bb) {
        int b = gw;
        float pa = 0.f;
        #pragma unroll
        for (int m = 0; m < 18; m++) {
            int k = l + 64 * m;   // 0..1151
            float vv = (k < 512) ? A.cto[b * 512 + k]
                     : (k < 768) ? A.h1o[b * 256 + k - 512]
                     : (k < 1024) ? A.c1o[b * 256 + k - 768]
                     : A.xw[b * 128 + k - 1024];
            pa += vv * A.Wpg[k];
        }
        pa = wave_red(pa);
        if (l == 0) A.pgo[b] = sigf(pa + A.bpg[0]);
    }
    grid.sync();

    // ---- P8: MFMA vocab GEMM, one 16-col tile per wave + fused tile M/S
    if (gw < NTILE) {
        int t = gw;
        int ln = l & 15, q = l >> 4;
        int vc = t * 16 + ln;                       // always < 50000
        const float* bptr = A.W2 + (size_t)vc * 256 + q * 8;
        const unsigned short* aptr = A.abf + ln * 256 + q * 8;
        f32x4 acc[8] = {};
        #pragma unroll
        for (int kk = 0; kk < 256; kk += 32) {
            float4 bv0 = *(const float4*)(bptr + kk);
            float4 bv1 = *(const float4*)(bptr + kk + 4);
            unsigned short bu[8] = {
                f2bf(bv0.x), f2bf(bv0.y), f2bf(bv0.z), f2bf(bv0.w),
                f2bf(bv1.x), f2bf(bv1.y), f2bf(bv1.z), f2bf(bv1.w)};
            bf16x8 bfr = __builtin_bit_cast(bf16x8, *(const bf16x8*)bu);
            #pragma unroll
            for (int mt = 0; mt < 8; mt++) {
                bf16x8 afr = *(const bf16x8*)(aptr + mt * 4096 + kk);
                acc[mt] = __builtin_amdgcn_mfma_f32_16x16x32_bf16(afr, bfr, acc[mt], 0, 0, 0);
            }
        }
        float bias = A.b2[vc];
        #pragma unroll
        for (int mt = 0; mt < 8; mt++) {
            #pragma unroll
            for (int r = 0; r < 4; r++) {
                int row = mt * 16 + q * 4 + r;
                float v = acc[mt][r] + bias;
                A.fd[(size_t)row * VOo + vc] = v;
                float mx = v;
                mx = fmaxf(mx, __shfl_xor(mx, 1));
                mx = fmaxf(mx, __shfl_xor(mx, 2));
                mx = fmaxf(mx, __shfl_xor(mx, 4));
                mx = fmaxf(mx, __shfl_xor(mx, 8));
                float ev = __expf(v - mx);
                ev += __shfl_xor(ev, 1);
                ev += __shfl_xor(ev, 2);
                ev += __shfl_xor(ev, 4);
                ev += __shfl_xor(ev, 8);
                if (ln == 0) {
                    A.pM[(size_t)row * PSTR + t] = mx;
                    A.pS[(size_t)row * PSTR + t] = ev;
                }
            }
        }
    }
    grid.sync();

    // ---- P9: combine tile partials + normalize + p_gen scale + OOV tail
    {
        int b = g >> 1, half = g & 1;
        float m = -3.4e38f, s = 0.f;
        for (int i = tid; i < NTILE; i += 1024) {
            float mi = A.pM[(size_t)b * PSTR + i];
            float si = A.pS[(size_t)b * PSTR + i];
            float M2 = fmaxf(m, mi);
            s = s * __expf(m - M2) + si * __expf(mi - M2);
            m = M2;
        }
        #pragma unroll
        for (int off = 32; off; off >>= 1) {
            float mo = __shfl_down(m, off);
            float so = __shfl_down(s, off);
            float M2 = fmaxf(m, mo);
            s = s * __expf(m - M2) + so * __expf(mo - M2);
            m = M2;
        }
        if (l == 0) { s_red[wv] = m; s_av[wv] = s; }
        __syncthreads();
        if (tid == 0) {
            float M = s_red[0], S = s_av[0];
            for (int i = 1; i < 16; i++) {
                float M2 = fmaxf(M, s_red[i]);
                S = S * __expf(M - M2) + s_av[i] * __expf(s_red[i] - M2);
                M = M2;
            }
            s_b[0] = M; s_b[1] = S;
        }
        __syncthreads();
        float M = s_b[0];
        float scale = A.pgo[b] / s_b[1];
        float* lrow = A.fd + (size_t)b * VOo;
        int v0 = half * 25000;
        for (int v = v0 + tid; v < v0 + 25000; v += 1024)
            lrow[v] = __expf(lrow[v] - M) * scale;
        if (half == 1 && tid < OOVn)
            lrow[Vv + tid] = A.xz[b * OOVn + tid];
    }
    grid.sync();

    // ---- P10: pointer scatter-add
    {
        int fid = g * 1024 + tid;
        if (fid < Bb * TKk) {
            int b = fid / TKk;
            float w = (1.f - A.pgo[b]) * A.attno[fid];
            atomicAdd(A.fd + (size_t)b * VOo + A.ebev[fid], w);
        }
    }
}

extern "C" void kernel_launch(void* const* d_in, const int* in_sizes, int n_in,
                              void* d_out, int out_size, void* d_ws, size_t ws_size,
                              hipStream_t stream)
{
    (void)in_sizes; (void)n_in; (void)out_size; (void)ws_size;

    float* out   = (float*)d_out;
    float* fd    = out;                              // [B, VO]
    float* h1o   = out + (size_t)Bb * VOo;           // [B, H]
    float* c1o   = h1o + (size_t)Bb * Hh;            // [B, H]
    float* cto   = c1o + (size_t)Bb * Hh;            // [B, N2]
    float* attno = cto + (size_t)Bb * N2n;           // [B, TK]
    float* pgo   = attno + (size_t)Bb * TKk;         // [B]
    float* covo  = pgo + Bb;                         // [B, TK]

    float* ws  = (float*)d_ws;
    float* xw  = ws;                                 // [B,128]
    float* dfw = xw + (size_t)Bb * EMB;              // [B,512]
    float* scw = dfw + (size_t)Bb * N2n;             // [B,400]
    float* pMw = scw + (size_t)Bb * TKk;             // [128, PSTR]
    float* pSw = pMw + (size_t)Bb * PSTR;            // [128, PSTR]
    unsigned short* abf = (unsigned short*)(pSw + (size_t)Bb * PSTR); // [B,256] bf16

    MegaArgs a;
    a.y    = (const int*)d_in[0];
    a.h0   = (const float*)d_in[1];
    a.c0   = (const float*)d_in[2];
    a.eo   = (const float*)d_in[3];
    a.ef   = (const float*)d_in[4];
    a.mask = (const float*)d_in[5];
    a.ct1  = (const float*)d_in[6];
    a.xz   = (const float*)d_in[7];
    a.ebev = (const int*)d_in[8];
    a.covi = (const float*)d_in[9];
    a.emb  = (const float*)d_in[11];
    a.Wx   = (const float*)d_in[12];
    a.bx   = (const float*)d_in[13];
    a.wih  = (const float*)d_in[14];
    a.bih  = (const float*)d_in[15];
    a.whh  = (const float*)d_in[16];
    a.bhh  = (const float*)d_in[17];
    a.Wp   = (const float*)d_in[18];
    a.bp   = (const float*)d_in[19];
    a.vw   = (const float*)d_in[20];
    a.Wc   = (const float*)d_in[21];
    a.Wpg  = (const float*)d_in[22];
    a.bpg  = (const float*)d_in[23];
    a.W1   = (const float*)d_in[24];
    a.b1   = (const float*)d_in[25];
    a.W2   = (const float*)d_in[26];
    a.b2   = (const float*)d_in[27];
    a.h1o = h1o; a.c1o = c1o; a.cto = cto; a.attno = attno; a.covo = covo;
    a.pgo = pgo; a.fd = fd;
    a.xw = xw; a.dfw = dfw; a.scw = scw; a.pM = pMw; a.pS = pSw; a.abf = abf;

    void* kparams[] = { (void*)&a };
    hipLaunchCooperativeKernel((const void*)k_mega, dim3(GRID), dim3(1024),
                               kparams, 0, stream);
}